// Round 7
// baseline (2766.832 us; speedup 1.0000x reference)
//
#include <hip/hip_runtime.h>
#include <hip/hip_bf16.h>

typedef unsigned int       u32;
typedef unsigned long long u64;
typedef unsigned short     u16b;
typedef _Float16           f16;
typedef f16   f16x8v __attribute__((ext_vector_type(8)));
typedef float f32x4  __attribute__((ext_vector_type(4)));
struct U128 { u64 lo, hi; };

// Problem dims (all inputs/outputs are float32 per the reference)
#define BATCH 128
#define SLEN  512
#define IDIM  256
#define HDIM  256
#define GX_BYTES ((size_t)65536 * 1024 * 2)
// ws: gx f16 [65536][1024] | Hbuf f16 [2][128][256] | flags int [64]
#define HBUF_PAR 32768          // f16 elements per parity buffer

__device__ __forceinline__ float sigm(float x) {
    return __builtin_amdgcn_rcpf(1.0f + __expf(-x));
}
__device__ __forceinline__ float tanh_f(float x) {
    return 1.0f - 2.0f * __builtin_amdgcn_rcpf(__expf(2.0f * x) + 1.0f);
}
__device__ __forceinline__ f16x8v pack8(float4 a, float4 b) {
    f16x8v v;
    v[0] = (f16)a.x; v[1] = (f16)a.y; v[2] = (f16)a.z; v[3] = (f16)a.w;
    v[4] = (f16)b.x; v[5] = (f16)b.y; v[6] = (f16)b.z; v[7] = (f16)b.w;
    return v;
}

// ---------------------------------------------------------------------------
// Kernel 1: gates_x = x @ Wg[:, :256]^T + bg  -> f16 [65536][1024]
// (unchanged from round 5/6 — passing)
// ---------------------------------------------------------------------------
__global__ __launch_bounds__(256) void gemm_gx(
    const float* __restrict__ X,
    const float* __restrict__ Wf, const float* __restrict__ Wi,
    const float* __restrict__ Wc, const float* __restrict__ Wo,
    const float* __restrict__ bf_, const float* __restrict__ bi_,
    const float* __restrict__ bc_, const float* __restrict__ bo_,
    f16* __restrict__ gx) {
    __shared__ _Float16 As[128 * 40];
    __shared__ _Float16 Bs[128 * 40];
    __shared__ float bias_lds[128];

    const int tid = threadIdx.x;
    const int wgy = blockIdx.y;
    const size_t m0 = (size_t)blockIdx.x * 128;

    const float* Wsel[4] = {Wf, Wi, Wc, Wo};
    const float* bsel[4] = {bf_, bi_, bc_, bo_};
    const float* Wseg = Wsel[wgy >> 1];
    const int row_off = (wgy & 1) * 128;

    if (tid < 128) bias_lds[tid] = bsel[wgy >> 1][row_off + tid];

    const int r  = tid >> 2;
    const int c8 = (tid & 3) * 8;

    const float* Ap0 = X + (m0 + r) * 256 + c8;
    const float* Ap1 = Ap0 + 64 * 256;
    const float* Bp0 = Wseg + (size_t)(row_off + r) * 512 + c8;
    const float* Bp1 = Bp0 + 64 * 512;

    const int lane = tid & 63;
    const int w    = tid >> 6;
    const int wm = w >> 1, wn = w & 1;
    const int col = lane & 15, quad = lane >> 4;

    f32x4 acc[4][4] = {};

    for (int kc = 0; kc < 8; kc++) {
        const int kk = kc * 32;
        float4 a00 = *(const float4*)(Ap0 + kk);
        float4 a01 = *(const float4*)(Ap0 + kk + 4);
        float4 a10 = *(const float4*)(Ap1 + kk);
        float4 a11 = *(const float4*)(Ap1 + kk + 4);
        float4 b00 = *(const float4*)(Bp0 + kk);
        float4 b01 = *(const float4*)(Bp0 + kk + 4);
        float4 b10 = *(const float4*)(Bp1 + kk);
        float4 b11 = *(const float4*)(Bp1 + kk + 4);
        __syncthreads();
        *(f16x8v*)&As[r * 40 + c8]        = pack8(a00, a01);
        *(f16x8v*)&As[(r + 64) * 40 + c8] = pack8(a10, a11);
        *(f16x8v*)&Bs[r * 40 + c8]        = pack8(b00, b01);
        *(f16x8v*)&Bs[(r + 64) * 40 + c8] = pack8(b10, b11);
        __syncthreads();
        f16x8v a[4], b[4];
        #pragma unroll
        for (int i = 0; i < 4; i++)
            a[i] = *(const f16x8v*)&As[(wm * 64 + i * 16 + col) * 40 + quad * 8];
        #pragma unroll
        for (int j = 0; j < 4; j++)
            b[j] = *(const f16x8v*)&Bs[(wn * 64 + j * 16 + col) * 40 + quad * 8];
        #pragma unroll
        for (int i = 0; i < 4; i++)
            #pragma unroll
            for (int j = 0; j < 4; j++)
                acc[i][j] = __builtin_amdgcn_mfma_f32_16x16x32_f16(a[i], b[j], acc[i][j], 0, 0, 0);
    }

    #pragma unroll
    for (int i = 0; i < 4; i++) {
        #pragma unroll
        for (int j = 0; j < 4; j++) {
            #pragma unroll
            for (int rg = 0; rg < 4; rg++) {
                const size_t m = m0 + wm * 64 + i * 16 + quad * 4 + rg;
                const int nl = wn * 64 + j * 16 + col;
                gx[m * 1024 + (size_t)wgy * 128 + nl] = (f16)(acc[i][j][rg] + bias_lds[nl]);
            }
        }
    }
}

// ---------------------------------------------------------------------------
// Kernel 2: cross-WG sliced recurrence. 64 WGs = 8 batch-groups x 8 slices.
// WG (gb,s): batches [16gb,16gb+16), units [32s,32s+32), all 4 gates.
// Per step: gather full h (agent-coherent 8B loads, parity-double-buffered),
// 16 MFMA/wave (M=16 batches dense), 4-lane XOR-transpose to collect gates,
// activations, publish 1KB h-slice (agent 8B stores), barrier (vmcnt drain =
// global visibility), flag[gb][s] = t+1. Readers spin signed (flag < t) —
// 0xAA ws-poison is negative, so no init pass needed. Flag protocol bounds
// inter-WG skew to 1 step, making the 2-parity h buffer race-free.
// Co-residency: 64 WGs <= 256 CUs, all resident at dispatch.
// ---------------------------------------------------------------------------
__global__ __launch_bounds__(256) void lstm_rec(
    const float* __restrict__ Wf, const float* __restrict__ Wi,
    const float* __restrict__ Wc, const float* __restrict__ Wo,
    const f16* __restrict__ gx,
    const float* __restrict__ Wout, const float* __restrict__ bout,
    float* __restrict__ out,
    f16* __restrict__ Hbuf, int* __restrict__ flags) {
    const int tid  = threadIdx.x;
    const int gb   = blockIdx.x >> 3;
    const int s    = blockIdx.x & 7;
    const int w    = tid >> 6;
    const int l    = tid & 63;
    const int l15  = l & 15;
    const int quad = l >> 4;
    const int e    = l & 3;
    const int q4   = (l >> 2) & 3;

    // --- B-fragments: wave w owns WG-cols [32w,32w+32) = 2 N-tiles.
    // col cw -> gate cw&3 (== e), unit 32s + (cw>>2). Lane l: N-row = tile
    // base + l15, k = kt*32 + quad*8 (8 f16 from the W row's h-part).
    const float* Wsel4[4] = {Wf, Wi, Wc, Wo};
    f16x8v B[2][8];
    #pragma unroll
    for (int ti = 0; ti < 2; ti++) {
        const int cw = 32 * w + 16 * ti + l15;
        const float* row = Wsel4[cw & 3] + (size_t)(32 * s + (cw >> 2)) * 512 + 256 + quad * 8;
        #pragma unroll
        for (int kt = 0; kt < 8; kt++) {
            float4 x0 = *(const float4*)(row + kt * 32);
            float4 x1 = *(const float4*)(row + kt * 32 + 4);
            B[ti][kt] = pack8(x0, x1);
        }
    }

    // cell ownership: lane handles (batch bq, unit u(ti)) for ti=0,1
    const int bq  = quad * 4 + e;          // batch row 0..15
    const int ul0 = 8 * w + q4;            // u_local, ti=0
    const int ul1 = ul0 + 4;               // u_local, ti=1
    const f16* gxb = gx + ((size_t)(16 * gb + bq) * 512) * 1024 + 32 * s;
    int* myflag = &flags[gb * 8 + s];
    int* spinflag = &flags[gb * 8 + (tid & 7)];

    float c0 = 0.0f, c1 = 0.0f;

    for (int t = 0; t < 512; t++) {
        // x-gate preactivations for this step (issue before the spin)
        f16 xg0[4], xg1[4];
        #pragma unroll
        for (int g = 0; g < 4; g++) {
            xg0[g] = gxb[(size_t)t * 1024 + g * 256 + ul0];
            xg1[g] = gxb[(size_t)t * 1024 + g * 256 + ul1];
        }

        f32x4 acc0 = {0.f, 0.f, 0.f, 0.f}, acc1 = {0.f, 0.f, 0.f, 0.f};
        if (t > 0) {
            if (tid < 8) {
                while (__hip_atomic_load(spinflag, __ATOMIC_ACQUIRE,
                                         __HIP_MEMORY_SCOPE_AGENT) < t)
                    __builtin_amdgcn_s_sleep(1);
            }
            __syncthreads();
            // gather h_t: lane reads A-frag rows = batch l15, k = kt*32+quad*8
            const u64* hrow = (const u64*)(Hbuf + (size_t)(t & 1) * HBUF_PAR
                                           + (size_t)(16 * gb + l15) * 256);
            #pragma unroll
            for (int kt = 0; kt < 8; kt++) {
                u64 lo = __hip_atomic_load((u64*)(hrow + kt * 8 + quad * 2),
                                           __ATOMIC_RELAXED, __HIP_MEMORY_SCOPE_AGENT);
                u64 hi = __hip_atomic_load((u64*)(hrow + kt * 8 + quad * 2 + 1),
                                           __ATOMIC_RELAXED, __HIP_MEMORY_SCOPE_AGENT);
                U128 p{lo, hi};
                f16x8v A = __builtin_bit_cast(f16x8v, p);
                acc0 = __builtin_amdgcn_mfma_f32_16x16x32_f16(A, B[0][kt], acc0, 0, 0, 0);
                acc1 = __builtin_amdgcn_mfma_f32_16x16x32_f16(A, B[1][kt], acc1, 0, 0, 0);
            }
        }

        // --- 4-lane XOR transpose + activations, per tile ---
        const bool s0 = (e & 1) != 0, s1 = (e & 2) != 0;
        u32 hpack[2];
        #pragma unroll
        for (int ti = 0; ti < 2; ti++) {
            f32x4 A_ = ti ? acc1 : acc0;
            float a0 = A_[0], a1 = A_[1], a2 = A_[2], a3 = A_[3];
            // x_d = A_[e^d]
            float x0 = s1 ? (s0 ? a3 : a2) : (s0 ? a1 : a0);
            float x1 = s1 ? (s0 ? a2 : a3) : (s0 ? a0 : a1);
            float x2 = s1 ? (s0 ? a1 : a0) : (s0 ? a3 : a2);
            float x3 = s1 ? (s0 ? a0 : a1) : (s0 ? a2 : a3);
            // v_d = gate (e^d) value at row bq (from lane l^d)
            float v0 = x0;
            float v1 = __shfl_xor(x1, 1);
            float v2 = __shfl_xor(x2, 2);
            float v3 = __shfl_xor(x3, 3);
            // gate g lives at v[(e)^g]
            float F  = s1 ? (s0 ? v3 : v2) : (s0 ? v1 : v0);
            float I_ = s1 ? (s0 ? v2 : v3) : (s0 ? v0 : v1);
            float G_ = s1 ? (s0 ? v1 : v0) : (s0 ? v3 : v2);
            float O_ = s1 ? (s0 ? v0 : v1) : (s0 ? v2 : v3);
            const f16* xg = ti ? xg1 : xg0;
            float gf = (float)xg[0] + F;
            float gi = (float)xg[1] + I_;
            float gg = (float)xg[2] + G_;
            float go = (float)xg[3] + O_;
            float sf = sigm(gf), si = sigm(gi), so = sigm(go);
            float tg = tanh_f(gg);
            float& c = ti ? c1 : c0;
            c = c * sf + si * tg;
            float h = tanh_f(c) * so;
            hpack[ti] = (u32)__builtin_bit_cast(u16b, (f16)h);
        }

        // --- pack 4 units (q4 lanes) into 8B and publish ---
        f16* hout = Hbuf + (size_t)((t + 1) & 1) * HBUF_PAR
                  + (size_t)(16 * gb + bq) * 256 + 32 * s + 8 * w;
        #pragma unroll
        for (int ti = 0; ti < 2; ti++) {
            u32 m = hpack[ti];
            u32 p4 = (u32)__shfl_xor((int)m, 4);
            u32 pair = (q4 & 1) ? ((m << 16) | p4) : ((p4 << 16) | m);
            u32 p8 = (u32)__shfl_xor((int)pair, 8);
            u64 full = (q4 & 2) ? (((u64)pair << 32) | (u64)p8)
                                : (((u64)p8 << 32) | (u64)pair);
            if (q4 == 0)
                __hip_atomic_store((u64*)(hout + 4 * ti), full,
                                   __ATOMIC_RELAXED, __HIP_MEMORY_SCOPE_AGENT);
        }

        __syncthreads();   // drains vmcnt: agent stores acked at coherence point
        if (tid == 0)
            __hip_atomic_store(myflag, t + 1, __ATOMIC_RELEASE,
                               __HIP_MEMORY_SCOPE_AGENT);
    }

    // --- epilogue: slice-0 WG of each group computes out = H_512 @ Wout^T + b
    if (s == 0) {
        if (tid < 8) {
            while (__hip_atomic_load(spinflag, __ATOMIC_ACQUIRE,
                                     __HIP_MEMORY_SCOPE_AGENT) < 512)
                __builtin_amdgcn_s_sleep(1);
        }
        __syncthreads();
        __shared__ _Float16 hf[16 * 256];
        {
            const int bb = tid >> 4, seg = tid & 15;   // 32B per thread
            const u64* src = (const u64*)(Hbuf + (size_t)(16 * gb + bb) * 256 + seg * 16);
            u64* dst = (u64*)&hf[bb * 256 + seg * 16];
            #pragma unroll
            for (int q = 0; q < 4; q++)
                dst[q] = __hip_atomic_load((u64*)(src + q), __ATOMIC_RELAXED,
                                           __HIP_MEMORY_SCOPE_AGENT);
        }
        __syncthreads();
        const int bb = tid & 15, ob = (tid >> 4) * 8;
        const f16* hb = &hf[bb * 256];
        #pragma unroll
        for (int oo = 0; oo < 8; oo++) {
            const int o = ob + oo;
            float acc = bout[o];
            const float4* wr = (const float4*)(Wout + (size_t)o * 256);
            for (int q = 0; q < 64; q++) {
                float4 wv = wr[q];
                acc += wv.x * (float)hb[q * 4 + 0];
                acc += wv.y * (float)hb[q * 4 + 1];
                acc += wv.z * (float)hb[q * 4 + 2];
                acc += wv.w * (float)hb[q * 4 + 3];
            }
            out[(size_t)(16 * gb + bb) * 128 + o] = acc;
        }
    }
}

extern "C" void kernel_launch(void* const* d_in, const int* in_sizes, int n_in,
                              void* d_out, int out_size, void* d_ws, size_t ws_size,
                              hipStream_t stream) {
    const float* x    = (const float*)d_in[0];
    const float* Wf   = (const float*)d_in[1];
    const float* bfv  = (const float*)d_in[2];
    const float* Wi   = (const float*)d_in[3];
    const float* biv  = (const float*)d_in[4];
    const float* Wc   = (const float*)d_in[5];
    const float* bcv  = (const float*)d_in[6];
    const float* Wo   = (const float*)d_in[7];
    const float* bov  = (const float*)d_in[8];
    const float* Wout = (const float*)d_in[9];
    const float* bout = (const float*)d_in[10];

    f16* gx    = (f16*)d_ws;
    f16* Hbuf  = (f16*)((char*)d_ws + GX_BYTES);
    int* flags = (int*)((char*)d_ws + GX_BYTES + (size_t)2 * HBUF_PAR * 2);

    gemm_gx<<<dim3(512, 8), 256, 0, stream>>>(x, Wf, Wi, Wc, Wo, bfv, biv, bcv, bov, gx);
    lstm_rec<<<64, 256, 0, stream>>>(Wf, Wi, Wc, Wo, gx, Wout, bout,
                                     (float*)d_out, Hbuf, flags);
}

// Round 8
// 1361.490 us; speedup vs baseline: 2.0322x; 2.0322x over previous
//
#include <hip/hip_runtime.h>
#include <hip/hip_bf16.h>

typedef unsigned int u32;
typedef _Float16     f16;
typedef f16   f16x8v __attribute__((ext_vector_type(8)));
typedef float f32x4  __attribute__((ext_vector_type(4)));

#define BATCH 128
#define SLEN  512
#define IDIM  256
#define HDIM  256
#define GX_BYTES ((size_t)65536 * 1024 * 2)

__device__ __forceinline__ float sigm(float x) {
    return __builtin_amdgcn_rcpf(1.0f + __expf(-x));
}
__device__ __forceinline__ float tanh_f(float x) {
    return 1.0f - 2.0f * __builtin_amdgcn_rcpf(__expf(2.0f * x) + 1.0f);
}
__device__ __forceinline__ f16x8v pack8(float4 a, float4 b) {
    f16x8v v;
    v[0] = (f16)a.x; v[1] = (f16)a.y; v[2] = (f16)a.z; v[3] = (f16)a.w;
    v[4] = (f16)b.x; v[5] = (f16)b.y; v[6] = (f16)b.z; v[7] = (f16)b.w;
    return v;
}
__device__ __forceinline__ float sel4(int q, float a, float b, float c, float d) {
    return q == 0 ? a : (q == 1 ? b : (q == 2 ? c : d));
}

// ---------------------------------------------------------------------------
// Kernel 1: gates_x = x @ Wg[:, :256]^T + bg  -> f16 [65536][1024]
// (unchanged — passing)
// ---------------------------------------------------------------------------
__global__ __launch_bounds__(256) void gemm_gx(
    const float* __restrict__ X,
    const float* __restrict__ Wf, const float* __restrict__ Wi,
    const float* __restrict__ Wc, const float* __restrict__ Wo,
    const float* __restrict__ bf_, const float* __restrict__ bi_,
    const float* __restrict__ bc_, const float* __restrict__ bo_,
    f16* __restrict__ gx) {
    __shared__ _Float16 As[128 * 40];
    __shared__ _Float16 Bs[128 * 40];
    __shared__ float bias_lds[128];

    const int tid = threadIdx.x;
    const int wgy = blockIdx.y;
    const size_t m0 = (size_t)blockIdx.x * 128;

    const float* Wsel[4] = {Wf, Wi, Wc, Wo};
    const float* bsel[4] = {bf_, bi_, bc_, bo_};
    const float* Wseg = Wsel[wgy >> 1];
    const int row_off = (wgy & 1) * 128;

    if (tid < 128) bias_lds[tid] = bsel[wgy >> 1][row_off + tid];

    const int r  = tid >> 2;
    const int c8 = (tid & 3) * 8;

    const float* Ap0 = X + (m0 + r) * 256 + c8;
    const float* Ap1 = Ap0 + 64 * 256;
    const float* Bp0 = Wseg + (size_t)(row_off + r) * 512 + c8;
    const float* Bp1 = Bp0 + 64 * 512;

    const int lane = tid & 63;
    const int w    = tid >> 6;
    const int wm = w >> 1, wn = w & 1;
    const int col = lane & 15, quad = lane >> 4;

    f32x4 acc[4][4] = {};

    for (int kc = 0; kc < 8; kc++) {
        const int kk = kc * 32;
        float4 a00 = *(const float4*)(Ap0 + kk);
        float4 a01 = *(const float4*)(Ap0 + kk + 4);
        float4 a10 = *(const float4*)(Ap1 + kk);
        float4 a11 = *(const float4*)(Ap1 + kk + 4);
        float4 b00 = *(const float4*)(Bp0 + kk);
        float4 b01 = *(const float4*)(Bp0 + kk + 4);
        float4 b10 = *(const float4*)(Bp1 + kk);
        float4 b11 = *(const float4*)(Bp1 + kk + 4);
        __syncthreads();
        *(f16x8v*)&As[r * 40 + c8]        = pack8(a00, a01);
        *(f16x8v*)&As[(r + 64) * 40 + c8] = pack8(a10, a11);
        *(f16x8v*)&Bs[r * 40 + c8]        = pack8(b00, b01);
        *(f16x8v*)&Bs[(r + 64) * 40 + c8] = pack8(b10, b11);
        __syncthreads();
        f16x8v a[4], b[4];
        #pragma unroll
        for (int i = 0; i < 4; i++)
            a[i] = *(const f16x8v*)&As[(wm * 64 + i * 16 + col) * 40 + quad * 8];
        #pragma unroll
        for (int j = 0; j < 4; j++)
            b[j] = *(const f16x8v*)&Bs[(wn * 64 + j * 16 + col) * 40 + quad * 8];
        #pragma unroll
        for (int i = 0; i < 4; i++)
            #pragma unroll
            for (int j = 0; j < 4; j++)
                acc[i][j] = __builtin_amdgcn_mfma_f32_16x16x32_f16(a[i], b[j], acc[i][j], 0, 0, 0);
    }

    #pragma unroll
    for (int i = 0; i < 4; i++) {
        #pragma unroll
        for (int j = 0; j < 4; j++) {
            #pragma unroll
            for (int rg = 0; rg < 4; rg++) {
                const size_t m = m0 + wm * 64 + i * 16 + quad * 4 + rg;
                const int nl = wn * 64 + j * 16 + col;
                gx[m * 1024 + (size_t)wgy * 128 + nl] = (f16)(acc[i][j][rg] + bias_lds[nl]);
            }
        }
    }
}

// ---------------------------------------------------------------------------
// Kernel 2: the recurrence (round-6 structure + 3 wait-killers).
// 128 WGs x 256 thr (4 waves, 1 wave/SIMD). Wave w owns units [64w,64w+64).
// K-chunks processed in wave-local order kb[j]=(2w+j)&7: j=0,1 are the h
// values this wave itself just wrote (LDS same-wave ordering) -> 32 MFMAs
// run BEFORE the broadcast barrier, hiding publish+barrier latency.
// kt=0 MFMAs accumulate into a constant zero C (no per-step acc init).
// gx prefetch is pinned at step top with sched_barrier(0) so the scheduler
// cannot sink the ~900-cyc L2-miss loads to their use point.
// ---------------------------------------------------------------------------
__global__ __launch_bounds__(256, 1) void lstm_rec(
    const float* __restrict__ Wf, const float* __restrict__ Wi,
    const float* __restrict__ Wc, const float* __restrict__ Wo,
    const f16* __restrict__ gx,
    const float* __restrict__ Wout, const float* __restrict__ bout,
    float* __restrict__ out) {
    __shared__ int4 oL4[8192];                       // 128 KiB, fragment-order
    __shared__ _Float16 h16[256] __attribute__((aligned(16)));

    const int tid  = threadIdx.x;
    const int b    = blockIdx.x;
    const int w    = tid >> 6;
    const int l    = tid & 63;
    const int l15  = l & 15;
    const int quad = l >> 4;

    // --- stage o-gate h-weights into LDS in fragment order (conflict-free) ---
    {
        const float4* src = (const float4*)(Wo + (size_t)tid * 512 + 256);
        const int w_ = tid >> 6, a_ = (tid >> 4) & 3, l15_ = tid & 15;
        int4* dst = &oL4[(size_t)(w_ * 4 + a_) * 512 + l15_];
        #pragma unroll
        for (int kt = 0; kt < 8; kt++) {
            #pragma unroll
            for (int q = 0; q < 4; q++) {
                float4 x0 = src[kt * 8 + q * 2];
                float4 x1 = src[kt * 8 + q * 2 + 1];
                f16x8v v = pack8(x0, x1);
                dst[kt * 64 + q * 16] = __builtin_bit_cast(int4, v);
            }
        }
    }

    // wave-local k-chunk order: kb[j] = (2w + j) & 7 (j compile-time indexed)
    int kb[8];
    #pragma unroll
    for (int j = 0; j < 8; j++) kb[j] = (2 * w + j) & 7;

    // --- f/i/c h-weights -> MFMA B-fragments, stored in kb order ---
    f16x8v wB[12][8];
    {
        const float* gp[3] = {Wf, Wi, Wc};
        #pragma unroll
        for (int g = 0; g < 3; g++) {
            #pragma unroll
            for (int a = 0; a < 4; a++) {
                const int u = 64 * w + 16 * a + l15;
                const float* row = gp[g] + (size_t)u * 512 + 256 + quad * 8;
                #pragma unroll
                for (int j = 0; j < 8; j++) {
                    float4 x0 = *(const float4*)(row + kb[j] * 32);
                    float4 x1 = *(const float4*)(row + kb[j] * 32 + 4);
                    wB[g * 4 + a][j] = pack8(x0, x1);
                }
            }
        }
    }

    float c = 0.0f;
    h16[tid] = (f16)0.0f;

    const _Float16* hA = &h16[quad * 8];             // + kb*32
    const int4* oR = &oL4[(size_t)w * 2048 + l];     // + a*512 + kb*64
    const f16* gxr = gx + (size_t)b * 512 * 1024 + tid;

    // gx prefetch for t=0
    float pf  = (float)gxr[0];
    float pi_ = (float)gxr[256];
    float pg  = (float)gxr[512];
    float po  = (float)gxr[768];

    const f32x4 Zc = {0.f, 0.f, 0.f, 0.f};

    __syncthreads();     // h=0 visible everywhere

    for (int t = 0; t < 512; t++) {
        float gf = pf, gi = pi_, gg = pg, go = po;
        {   // branchless prefetch of next step's x-gates; pin issue position
            const f16* gn = gxr + (size_t)(t < 511 ? t + 1 : 511) * 1024;
            pf  = (float)gn[0];
            pi_ = (float)gn[256];
            pg  = (float)gn[512];
            po  = (float)gn[768];
        }
        __builtin_amdgcn_sched_barrier(0);

        f32x4 acc[16];
        f16x8v Ab[2];
        f16x8v Ob[2][4];

        // ---- j=0,1: own k-chunks (h written by this wave; no barrier needed)
        Ab[0] = *(const f16x8v*)&hA[kb[0] * 32];
        #pragma unroll
        for (int a = 0; a < 4; a++)
            Ob[0][a] = __builtin_bit_cast(f16x8v, oR[a * 512 + kb[0] * 64]);
        Ab[1] = *(const f16x8v*)&hA[kb[1] * 32];
        #pragma unroll
        for (int a = 0; a < 4; a++)
            Ob[1][a] = __builtin_bit_cast(f16x8v, oR[a * 512 + kb[1] * 64]);

        #pragma unroll
        for (int tt = 0; tt < 12; tt++)
            acc[tt] = __builtin_amdgcn_mfma_f32_16x16x32_f16(Ab[0], wB[tt][0], Zc, 0, 0, 0);
        #pragma unroll
        for (int a = 0; a < 4; a++)
            acc[12 + a] = __builtin_amdgcn_mfma_f32_16x16x32_f16(Ab[0], Ob[0][a], Zc, 0, 0, 0);
        #pragma unroll
        for (int tt = 0; tt < 12; tt++)
            acc[tt] = __builtin_amdgcn_mfma_f32_16x16x32_f16(Ab[1], wB[tt][1], acc[tt], 0, 0, 0);
        #pragma unroll
        for (int a = 0; a < 4; a++)
            acc[12 + a] = __builtin_amdgcn_mfma_f32_16x16x32_f16(Ab[1], Ob[1][a], acc[12 + a], 0, 0, 0);

        __syncthreads();      // all waves' h_t now visible (overlapped by 32 MFMAs)

        // ---- j=2..7: cross-wave k-chunks, rolling depth-1 prefetch
        Ab[0] = *(const f16x8v*)&hA[kb[2] * 32];
        #pragma unroll
        for (int a = 0; a < 4; a++)
            Ob[0][a] = __builtin_bit_cast(f16x8v, oR[a * 512 + kb[2] * 64]);

        #pragma unroll
        for (int j = 2; j < 8; j++) {
            const int cur = j & 1 ^ 0;   // j=2 -> slot 0, alternating
            const int nxt = cur ^ 1;
            if (j < 7) {
                Ab[nxt] = *(const f16x8v*)&hA[kb[j + 1] * 32];
                #pragma unroll
                for (int a = 0; a < 4; a++)
                    Ob[nxt][a] = __builtin_bit_cast(f16x8v, oR[a * 512 + kb[j + 1] * 64]);
            }
            #pragma unroll
            for (int tt = 0; tt < 12; tt++)
                acc[tt] = __builtin_amdgcn_mfma_f32_16x16x32_f16(Ab[cur], wB[tt][j], acc[tt], 0, 0, 0);
            #pragma unroll
            for (int a = 0; a < 4; a++)
                acc[12 + a] = __builtin_amdgcn_mfma_f32_16x16x32_f16(Ab[cur], Ob[cur][a], acc[12 + a], 0, 0, 0);
        }

        // extract this lane's unit (u = tid): gate tile = quad, reg 0
        float df = sel4(quad, acc[0][0],  acc[1][0],  acc[2][0],  acc[3][0]);
        float di = sel4(quad, acc[4][0],  acc[5][0],  acc[6][0],  acc[7][0]);
        float dg = sel4(quad, acc[8][0],  acc[9][0],  acc[10][0], acc[11][0]);
        float dd = sel4(quad, acc[12][0], acc[13][0], acc[14][0], acc[15][0]);

        float F = gf + df, I = gi + di, G = gg + dg, O = go + dd;
        float sf = sigm(F), si = sigm(I), so = sigm(O);
        float tg = tanh_f(G);
        c = c * sf + si * tg;
        float h = tanh_f(c) * so;

        __syncthreads();      // everyone done reading h_t
        h16[tid] = (f16)h;    // publish h_{t+1}; own wave may read it pre-barrier
    }

    __syncthreads();          // final h visible for the epilogue

    // out[b, :] = h_final @ Wout^T + bout   (fp32 output)
    if (tid < 128) {
        float acc = bout[tid];
        const float4* wv = (const float4*)(Wout + (size_t)tid * 256);
        #pragma unroll
        for (int q = 0; q < 64; q++) {
            float4 v = wv[q];
            acc += v.x * (float)h16[q * 4 + 0];
            acc += v.y * (float)h16[q * 4 + 1];
            acc += v.z * (float)h16[q * 4 + 2];
            acc += v.w * (float)h16[q * 4 + 3];
        }
        out[b * 128 + tid] = acc;
    }
}

extern "C" void kernel_launch(void* const* d_in, const int* in_sizes, int n_in,
                              void* d_out, int out_size, void* d_ws, size_t ws_size,
                              hipStream_t stream) {
    const float* x    = (const float*)d_in[0];
    const float* Wf   = (const float*)d_in[1];
    const float* bfv  = (const float*)d_in[2];
    const float* Wi   = (const float*)d_in[3];
    const float* biv  = (const float*)d_in[4];
    const float* Wc   = (const float*)d_in[5];
    const float* bcv  = (const float*)d_in[6];
    const float* Wo   = (const float*)d_in[7];
    const float* bov  = (const float*)d_in[8];
    const float* Wout = (const float*)d_in[9];
    const float* bout = (const float*)d_in[10];

    f16* gx = (f16*)d_ws;

    gemm_gx<<<dim3(512, 8), 256, 0, stream>>>(x, Wf, Wi, Wc, Wo, bfv, biv, bcv, bov, gx);
    lstm_rec<<<128, 256, 0, stream>>>(Wf, Wi, Wc, Wo, gx, Wout, bout, (float*)d_out);
}

// Round 9
// 930.810 us; speedup vs baseline: 2.9725x; 1.4627x over previous
//
#include <hip/hip_runtime.h>
#include <hip/hip_bf16.h>

typedef unsigned int u32;
typedef _Float16     f16;
typedef f16   f16x8v __attribute__((ext_vector_type(8)));
typedef float f32x4  __attribute__((ext_vector_type(4)));

#define BATCH 128
#define SLEN  512
#define IDIM  256
#define HDIM  256
#define GX_BYTES ((size_t)65536 * 1024 * 2)

__device__ __forceinline__ float sigm(float x) {
    return __builtin_amdgcn_rcpf(1.0f + __expf(-x));
}
__device__ __forceinline__ float tanh_f(float x) {
    return 1.0f - 2.0f * __builtin_amdgcn_rcpf(__expf(2.0f * x) + 1.0f);
}
__device__ __forceinline__ f16x8v pack8(float4 a, float4 b) {
    f16x8v v;
    v[0] = (f16)a.x; v[1] = (f16)a.y; v[2] = (f16)a.z; v[3] = (f16)a.w;
    v[4] = (f16)b.x; v[5] = (f16)b.y; v[6] = (f16)b.z; v[7] = (f16)b.w;
    return v;
}

// ---------------------------------------------------------------------------
// Kernel 1: gates_x = x @ Wg[:, :256]^T + bg  -> f16 [65536][1024]
// (unchanged — passing)
// ---------------------------------------------------------------------------
__global__ __launch_bounds__(256) void gemm_gx(
    const float* __restrict__ X,
    const float* __restrict__ Wf, const float* __restrict__ Wi,
    const float* __restrict__ Wc, const float* __restrict__ Wo,
    const float* __restrict__ bf_, const float* __restrict__ bi_,
    const float* __restrict__ bc_, const float* __restrict__ bo_,
    f16* __restrict__ gx) {
    __shared__ _Float16 As[128 * 40];
    __shared__ _Float16 Bs[128 * 40];
    __shared__ float bias_lds[128];

    const int tid = threadIdx.x;
    const int wgy = blockIdx.y;
    const size_t m0 = (size_t)blockIdx.x * 128;

    const float* Wsel[4] = {Wf, Wi, Wc, Wo};
    const float* bsel[4] = {bf_, bi_, bc_, bo_};
    const float* Wseg = Wsel[wgy >> 1];
    const int row_off = (wgy & 1) * 128;

    if (tid < 128) bias_lds[tid] = bsel[wgy >> 1][row_off + tid];

    const int r  = tid >> 2;
    const int c8 = (tid & 3) * 8;

    const float* Ap0 = X + (m0 + r) * 256 + c8;
    const float* Ap1 = Ap0 + 64 * 256;
    const float* Bp0 = Wseg + (size_t)(row_off + r) * 512 + c8;
    const float* Bp1 = Bp0 + 64 * 512;

    const int lane = tid & 63;
    const int w    = tid >> 6;
    const int wm = w >> 1, wn = w & 1;
    const int col = lane & 15, quad = lane >> 4;

    f32x4 acc[4][4] = {};

    for (int kc = 0; kc < 8; kc++) {
        const int kk = kc * 32;
        float4 a00 = *(const float4*)(Ap0 + kk);
        float4 a01 = *(const float4*)(Ap0 + kk + 4);
        float4 a10 = *(const float4*)(Ap1 + kk);
        float4 a11 = *(const float4*)(Ap1 + kk + 4);
        float4 b00 = *(const float4*)(Bp0 + kk);
        float4 b01 = *(const float4*)(Bp0 + kk + 4);
        float4 b10 = *(const float4*)(Bp1 + kk);
        float4 b11 = *(const float4*)(Bp1 + kk + 4);
        __syncthreads();
        *(f16x8v*)&As[r * 40 + c8]        = pack8(a00, a01);
        *(f16x8v*)&As[(r + 64) * 40 + c8] = pack8(a10, a11);
        *(f16x8v*)&Bs[r * 40 + c8]        = pack8(b00, b01);
        *(f16x8v*)&Bs[(r + 64) * 40 + c8] = pack8(b10, b11);
        __syncthreads();
        f16x8v a[4], b[4];
        #pragma unroll
        for (int i = 0; i < 4; i++)
            a[i] = *(const f16x8v*)&As[(wm * 64 + i * 16 + col) * 40 + quad * 8];
        #pragma unroll
        for (int j = 0; j < 4; j++)
            b[j] = *(const f16x8v*)&Bs[(wn * 64 + j * 16 + col) * 40 + quad * 8];
        #pragma unroll
        for (int i = 0; i < 4; i++)
            #pragma unroll
            for (int j = 0; j < 4; j++)
                acc[i][j] = __builtin_amdgcn_mfma_f32_16x16x32_f16(a[i], b[j], acc[i][j], 0, 0, 0);
    }

    #pragma unroll
    for (int i = 0; i < 4; i++) {
        #pragma unroll
        for (int j = 0; j < 4; j++) {
            #pragma unroll
            for (int rg = 0; rg < 4; rg++) {
                const size_t m = m0 + wm * 64 + i * 16 + quad * 4 + rg;
                const int nl = wn * 64 + j * 16 + col;
                gx[m * 1024 + (size_t)wgy * 128 + nl] = (f16)(acc[i][j][rg] + bias_lds[nl]);
            }
        }
    }
}

// ---------------------------------------------------------------------------
// Kernel 2: the recurrence — 8 waves, 2 per SIMD (the TLP fix).
// 128 WGs x 512 thr. Wave w owns units [32w, 32w+32) = 8 N-tiles
// (f0,f1,i0,i1,c0,c1 B-frags AGPR-resident = 192 regs; o0,o1 streamed from
// conflict-free fragment-order LDS, 16 b128/wave/step). 2 waves/SIMD lets
// one wave's MFMA issue cover the other's LDS waits — rounds 6-8 proved a
// single wave serializes them (MfmaUtil pinned at 18.5%).
// Extraction: rows of D are replicated (A = h broadcast), so lane l holds
// unit u = 32w + 16*(quad&1) + l15 at acc[tile + (quad&1)][0] directly.
// ---------------------------------------------------------------------------
__global__ __launch_bounds__(512, 2) void lstm_rec(
    const float* __restrict__ Wf, const float* __restrict__ Wi,
    const float* __restrict__ Wc, const float* __restrict__ Wo,
    const f16* __restrict__ gx,
    const float* __restrict__ Wout, const float* __restrict__ bout,
    float* __restrict__ out) {
    __shared__ int4 oL4[8192];                       // 128 KiB fragment-order
    __shared__ _Float16 h16[256] __attribute__((aligned(16)));

    const int tid  = threadIdx.x;
    const int b    = blockIdx.x;
    const int w    = tid >> 6;        // wave 0..7
    const int l    = tid & 63;
    const int l15  = l & 15;
    const int quad = l >> 4;
    const int e2   = quad & 1;        // unit-half this lane extracts

    // --- stage o-gate h-weights into LDS, fragment order ---
    // slot((w,ti),kt,lane) = (w*2+ti)*512 + kt*64 + quad*16 + l15, int4 = 8 f16
    // covering Wo row u = 32w+16ti+l15, k = kt*32 + quad*8.
    {
        const int u     = tid >> 1;          // 0..255
        const int halfk = tid & 1;           // kt in [4*halfk, 4*halfk+4)
        const int sw = u >> 5, sti = (u >> 4) & 1, sl = u & 15;
        const float* src = Wo + (size_t)u * 512 + 256;
        int4* dst = &oL4[(size_t)(sw * 2 + sti) * 512 + sl];
        #pragma unroll
        for (int kk = 0; kk < 4; kk++) {
            const int kt = 4 * halfk + kk;
            #pragma unroll
            for (int q = 0; q < 4; q++) {
                float4 x0 = *(const float4*)(src + kt * 32 + q * 8);
                float4 x1 = *(const float4*)(src + kt * 32 + q * 8 + 4);
                f16x8v v = pack8(x0, x1);
                dst[kt * 64 + q * 16] = __builtin_bit_cast(int4, v);
            }
        }
    }

    // --- f/i/c B-fragments, AGPR-resident: wB[g*2+ti][kt] ---
    f16x8v wB[6][8];
    {
        const float* gp[3] = {Wf, Wi, Wc};
        #pragma unroll
        for (int g = 0; g < 3; g++) {
            #pragma unroll
            for (int ti = 0; ti < 2; ti++) {
                const int u = 32 * w + 16 * ti + l15;
                const float* row = gp[g] + (size_t)u * 512 + 256 + quad * 8;
                #pragma unroll
                for (int kt = 0; kt < 8; kt++) {
                    float4 x0 = *(const float4*)(row + kt * 32);
                    float4 x1 = *(const float4*)(row + kt * 32 + 4);
                    wB[g * 2 + ti][kt] = pack8(x0, x1);
                }
            }
        }
    }

    const int u = 32 * w + 16 * e2 + l15;   // the unit this lane owns
    float c = 0.0f;
    if (tid < 256) h16[tid] = (f16)0.0f;

    const _Float16* hA = &h16[quad * 8];             // + kt*32
    const int4* oR0 = &oL4[(size_t)(w * 2 + 0) * 512 + l];   // + kt*64
    const int4* oR1 = &oL4[(size_t)(w * 2 + 1) * 512 + l];
    const f16* gxr = gx + (size_t)b * 512 * 1024 + u;

    // gx prefetch for t=0
    float pf  = (float)gxr[0];
    float pi_ = (float)gxr[256];
    float pg  = (float)gxr[512];
    float po  = (float)gxr[768];

    const f32x4 Zc = {0.f, 0.f, 0.f, 0.f};

    __syncthreads();     // h=0 + oL4 visible

    for (int t = 0; t < 512; t++) {
        float gf = pf, gi = pi_, gg = pg, go = po;
        {   // branchless prefetch of next step's x-gates
            const f16* gn = gxr + (size_t)(t < 511 ? t + 1 : 511) * 1024;
            pf  = (float)gn[0];
            pi_ = (float)gn[256];
            pg  = (float)gn[512];
            po  = (float)gn[768];
        }

        f32x4 acc[8];
        #pragma unroll
        for (int kt = 0; kt < 8; kt++) {
            f16x8v A = *(const f16x8v*)&hA[kt * 32];
            if (kt == 0) {
                #pragma unroll
                for (int tt = 0; tt < 6; tt++)
                    acc[tt] = __builtin_amdgcn_mfma_f32_16x16x32_f16(A, wB[tt][0], Zc, 0, 0, 0);
                f16x8v o0 = __builtin_bit_cast(f16x8v, oR0[0]);
                acc[6] = __builtin_amdgcn_mfma_f32_16x16x32_f16(A, o0, Zc, 0, 0, 0);
                f16x8v o1 = __builtin_bit_cast(f16x8v, oR1[0]);
                acc[7] = __builtin_amdgcn_mfma_f32_16x16x32_f16(A, o1, Zc, 0, 0, 0);
            } else {
                #pragma unroll
                for (int tt = 0; tt < 6; tt++)
                    acc[tt] = __builtin_amdgcn_mfma_f32_16x16x32_f16(A, wB[tt][kt], acc[tt], 0, 0, 0);
                f16x8v o0 = __builtin_bit_cast(f16x8v, oR0[kt * 64]);
                acc[6] = __builtin_amdgcn_mfma_f32_16x16x32_f16(A, o0, acc[6], 0, 0, 0);
                f16x8v o1 = __builtin_bit_cast(f16x8v, oR1[kt * 64]);
                acc[7] = __builtin_amdgcn_mfma_f32_16x16x32_f16(A, o1, acc[7], 0, 0, 0);
            }
        }

        // rows replicated: lane's unit value = reg 0 of its half's tile
        float df = e2 ? acc[1][0] : acc[0][0];
        float di = e2 ? acc[3][0] : acc[2][0];
        float dg = e2 ? acc[5][0] : acc[4][0];
        float dd = e2 ? acc[7][0] : acc[6][0];

        float F = gf + df, I = gi + di, G = gg + dg, O = go + dd;
        float sf = sigm(F), si = sigm(I), so = sigm(O);
        float tg = tanh_f(G);
        c = c * sf + si * tg;
        float h = tanh_f(c) * so;

        __syncthreads();              // everyone done reading h_t
        if (quad < 2) h16[u] = (f16)h;   // quads 2,3 hold duplicates
        __syncthreads();              // h_{t+1} visible
    }

    // out[b, :] = h_final @ Wout^T + bout   (fp32 output)
    if (tid < 128) {
        float acc = bout[tid];
        const float4* wv = (const float4*)(Wout + (size_t)tid * 256);
        #pragma unroll
        for (int q = 0; q < 64; q++) {
            float4 v = wv[q];
            acc += v.x * (float)h16[q * 4 + 0];
            acc += v.y * (float)h16[q * 4 + 1];
            acc += v.z * (float)h16[q * 4 + 2];
            acc += v.w * (float)h16[q * 4 + 3];
        }
        out[b * 128 + tid] = acc;
    }
}

extern "C" void kernel_launch(void* const* d_in, const int* in_sizes, int n_in,
                              void* d_out, int out_size, void* d_ws, size_t ws_size,
                              hipStream_t stream) {
    const float* x    = (const float*)d_in[0];
    const float* Wf   = (const float*)d_in[1];
    const float* bfv  = (const float*)d_in[2];
    const float* Wi   = (const float*)d_in[3];
    const float* biv  = (const float*)d_in[4];
    const float* Wc   = (const float*)d_in[5];
    const float* bcv  = (const float*)d_in[6];
    const float* Wo   = (const float*)d_in[7];
    const float* bov  = (const float*)d_in[8];
    const float* Wout = (const float*)d_in[9];
    const float* bout = (const float*)d_in[10];

    f16* gx = (f16*)d_ws;

    gemm_gx<<<dim3(512, 8), 256, 0, stream>>>(x, Wf, Wi, Wc, Wo, bfv, biv, bcv, bov, gx);
    lstm_rec<<<128, 512, 0, stream>>>(Wf, Wi, Wc, Wo, gx, Wout, bout, (float*)d_out);
}